// Round 4
// baseline (264.357 us; speedup 1.0000x reference)
//
#include <hip/hip_runtime.h>

namespace {

constexpr int MM = 3;
constexpr int BB = 16384;
constexpr int DD = 1024;
constexpr int CC = 100;
constexpr int HH = 2048;             // 2*DD
constexpr int DESIRED = BB / CC;     // 163
constexpr int RLS = 2048;            // rowlist stride per class
constexpr int RS  = 4;               // gather row-chunks per (c,m)

// mega1 block partition
constexpr int NCOPY = 1536;          // 512 per modality, sequential copy
constexpr int NGATH = CC * MM * RS;  // 1200 read-only gather blocks
constexpr int DBS   = 4;             // base d-splits
constexpr int NBASE = (HH / 256) * DBS * MM;  // 96
constexpr int NMEGA1 = NCOPY + NGATH + NBASE;

// ws byte offsets (total < 10 MB)
constexpr size_t WS_COUNTS  = 0;                    // 128 int
constexpr size_t WS_GEN     = 512;                  // 128 int
constexpr size_t WS_OFF     = 1024;                 // 128 int
constexpr size_t WS_BPART   = 2048;                 // DBS*MM*HH f32 (96 KB)
constexpr size_t WS_MASK    = 2048 + 98304;         // CC*MM f32
constexpr size_t WS_PROTO   = 102400;               // CC*MM*DD f32 (1.2 MB)
constexpr size_t WS_ROWLIST = 1331200;              // CC*RLS int (800 KB)
constexpr size_t WS_ACT     = 2150400;              // MM*CC*HH f32 (2.4 MB)
constexpr size_t WS_PSUM    = 4608000;              // CC*MM*RS*DD f32 (4.9 MB)

// One block: counts (LDS atomics), rowlist, gen/off prefix, labels out, loss.
__global__ void __launch_bounds__(1024)
k_plan_all(const int* __restrict__ labels, const float* __restrict__ dw,
           int* __restrict__ counts, int* __restrict__ gen,
           int* __restrict__ off, int* __restrict__ rowlist,
           float* __restrict__ out_lab_head, float* __restrict__ out_lab_tail,
           float* __restrict__ out_loss, int N) {
  __shared__ int scnt[128], spos[128], s[128];
  int t = threadIdx.x;
  if (t < 128) { scnt[t] = 0; spos[t] = 0; }
  __syncthreads();
  for (int b = t; b < BB; b += 1024) {
    int l = labels[b];
    atomicAdd(&scnt[l], 1);
    out_lab_head[b] = (float)l;
  }
  __syncthreads();
  for (int b = t; b < BB; b += 1024) {
    int l = labels[b];
    int pos = atomicAdd(&spos[l], 1);
    if (pos < RLS) rowlist[l * RLS + pos] = b;
  }
  // prefix scan of gen over classes (first 128 threads)
  int g = 0;
  if (t < CC) { int cnt = scnt[t]; g = cnt > 0 ? max(DESIRED - cnt, 0) : 0; }
  if (t < 128) s[t] = g;
  __syncthreads();
  for (int o = 1; o < 128; o <<= 1) {
    int v = (t < 128 && t >= o) ? s[t - o] : 0;
    __syncthreads();
    if (t < 128) s[t] += v;
    __syncthreads();
  }
  if (t < CC) {
    int excl = s[t] - g;
    counts[t] = scnt[t];
    gen[t] = g;
    off[t] = excl;
    for (int k = 0; k < g; ++k) out_lab_tail[excl + k] = (float)t;
  }
  if (t == 0) *out_loss = (N > 0) ? 0.1f * dw[0] : 0.0f;
}

// Horizontally fused: sequential copy || read-only class gather || base matvec.
__global__ void __launch_bounds__(256)
k_mega1(const float* __restrict__ feat, const float* __restrict__ fused,
        const float* __restrict__ W1, const int* __restrict__ rowlist,
        const int* __restrict__ counts, float* __restrict__ out,
        float* __restrict__ psum, float* __restrict__ bpart, int BN) {
  int bid = blockIdx.x, t = threadIdx.x;
  if (bid < NCOPY) {
    // ---- sequential copy: features[m] -> out rows [0, BB) of modality m ----
    int m = bid / 512, cb = bid % 512;
    const float4* src = reinterpret_cast<const float4*>(feat + (size_t)m * BB * DD);
    float4* dst = reinterpret_cast<float4*>(out + (size_t)m * BN * DD);
    size_t i0 = (size_t)cb * 256 + t;
    constexpr size_t S = 512 * 256;   // 131072 threads per modality
    // BB*DD/4 = 4194304 = 32*S
#pragma unroll
    for (int k = 0; k < 8; ++k) {
      float4 v0 = src[i0 + (4 * k + 0) * S];
      float4 v1 = src[i0 + (4 * k + 1) * S];
      float4 v2 = src[i0 + (4 * k + 2) * S];
      float4 v3 = src[i0 + (4 * k + 3) * S];
      dst[i0 + (4 * k + 0) * S] = v0;
      dst[i0 + (4 * k + 1) * S] = v1;
      dst[i0 + (4 * k + 2) * S] = v2;
      dst[i0 + (4 * k + 3) * S] = v3;
    }
  } else if (bid < NCOPY + NGATH) {
    // ---- read-only gather: partial class sums -> psum[c][m][rs][DD] ----
    int b2 = bid - NCOPY;
    int c = b2 % CC, mrs = b2 / CC;
    int m = mrs % MM, rs = mrs / MM;
    int cnt = min(counts[c], RLS);
    int lo = (cnt * rs) / RS, hi = (cnt * (rs + 1)) / RS;
    const int* rl = rowlist + c * RLS;
    int d0 = t * 4;
    const float* fb = feat + (size_t)m * BB * DD + d0;
    float4 a = {0.f, 0.f, 0.f, 0.f};
    int i = lo;
    for (; i + 4 <= hi; i += 4) {
      int r0 = rl[i], r1 = rl[i + 1], r2 = rl[i + 2], r3 = rl[i + 3];
      const float4 v0 = *reinterpret_cast<const float4*>(fb + (size_t)r0 * DD);
      const float4 v1 = *reinterpret_cast<const float4*>(fb + (size_t)r1 * DD);
      const float4 v2 = *reinterpret_cast<const float4*>(fb + (size_t)r2 * DD);
      const float4 v3 = *reinterpret_cast<const float4*>(fb + (size_t)r3 * DD);
      a.x += v0.x + v1.x + v2.x + v3.x;
      a.y += v0.y + v1.y + v2.y + v3.y;
      a.z += v0.z + v1.z + v2.z + v3.z;
      a.w += v0.w + v1.w + v2.w + v3.w;
    }
    for (; i < hi; ++i) {
      const float4 v = *reinterpret_cast<const float4*>(fb + (size_t)rl[i] * DD);
      a.x += v.x; a.y += v.y; a.z += v.z; a.w += v.w;
    }
    *reinterpret_cast<float4*>(
        &psum[(((size_t)c * MM + m) * RS + rs) * DD + d0]) = a;
  } else {
    // ---- base partials: bpart[db][m][j] = sum_{d in chunk} fused[d]*W1[m][d][j]
    int b3 = bid - NCOPY - NGATH;
    int jb = b3 % (HH / 256), db = (b3 / (HH / 256)) % DBS, m = b3 / ((HH / 256) * DBS);
    int j = jb * 256 + t;
    const float* w = W1 + ((size_t)m * (DD + CC)) * HH + j;
    float acc = 0.f;
    int dlo = db * (DD / DBS);
#pragma unroll 8
    for (int d = dlo; d < dlo + DD / DBS; ++d)
      acc = fmaf(fused[d], w[(size_t)d * HH], acc);
    bpart[((size_t)db * MM + m) * HH + j] = acc;
  }
}

// proto+mask (blocks 0..299)  ||  LN-activation -> act[m][c][j] (blocks 300..599)
__global__ void __launch_bounds__(256)
k_mega2(const float* __restrict__ psum, const int* __restrict__ counts,
        const float* __restrict__ bpart, const float* __restrict__ W1,
        const float* __restrict__ b1, const float* __restrict__ lng,
        const float* __restrict__ lnb, float* __restrict__ proto,
        float* __restrict__ mask, float* __restrict__ act) {
  __shared__ float r1[256], r2[256];
  int bid = blockIdx.x, t = threadIdx.x;
  if (bid < CC * MM) {
    int c = bid % CC, m = bid / CC;
    int d0 = t * 4;
    float4 a = {0.f, 0.f, 0.f, 0.f};
#pragma unroll
    for (int rs = 0; rs < RS; ++rs) {
      const float4 v = *reinterpret_cast<const float4*>(
          &psum[(((size_t)c * MM + m) * RS + rs) * DD + d0]);
      a.x += v.x; a.y += v.y; a.z += v.z; a.w += v.w;
    }
    int cnt = counts[c];
    float inv = cnt > 0 ? 1.f / (float)cnt : 0.f;
    a.x *= inv; a.y *= inv; a.z *= inv; a.w *= inv;
    *reinterpret_cast<float4*>(&proto[((size_t)c * MM + m) * DD + d0]) = a;
    r1[t] = a.x + a.y + a.z + a.w;
    __syncthreads();
    for (int o = 128; o > 0; o >>= 1) {
      if (t < o) r1[t] += r1[t + o];
      __syncthreads();
    }
    if (t == 0) mask[c * MM + m] = (r1[0] > 0.f) ? 1.f : 0.f;
  } else {
    int b2 = bid - CC * MM;
    int c = b2 % CC, m = b2 / CC;
    const float* w1row = W1 + ((size_t)m * (DD + CC) + DD + c) * HH;
    float h[8];
    float s = 0.f, s2 = 0.f;
#pragma unroll
    for (int k = 0; k < 8; ++k) {
      int j = t + k * 256;
      float base = bpart[(size_t)(0 * MM + m) * HH + j]
                 + bpart[(size_t)(1 * MM + m) * HH + j]
                 + bpart[(size_t)(2 * MM + m) * HH + j]
                 + bpart[(size_t)(3 * MM + m) * HH + j];
      float v = base + w1row[j] + b1[m * HH + j];
      h[k] = v; s += v; s2 += v * v;
    }
    r1[t] = s; r2[t] = s2;
    __syncthreads();
    for (int o = 128; o > 0; o >>= 1) {
      if (t < o) { r1[t] += r1[t + o]; r2[t] += r2[t + o]; }
      __syncthreads();
    }
    float mu = r1[0] * (1.f / HH);
    float var = r2[0] * (1.f / HH) - mu * mu;
    float rstd = rsqrtf(var + 1e-5f);
    float* ao = act + ((size_t)m * CC + c) * HH;
#pragma unroll
    for (int k = 0; k < 8; ++k) {
      int j = t + k * 256;
      float v = (h[k] - mu) * rstd * lng[m * HH + j] + lnb[m * HH + j];
      v = v > 0.f ? v : 0.2f * v;
      ao[j] = v;   // [m][c][j], j-contiguous
    }
  }
}

// Full-K GEMM for one (c, m, d-chunk) + bias + blend + scatter to output rows.
// 256 threads = 4 j-quarters x 64 lanes; lane covers 4 d via float4.
__global__ void __launch_bounds__(256)
k_gemm_final(const float* __restrict__ act, const float* __restrict__ W2,
             const float* __restrict__ b2, const float* __restrict__ proto,
             const float* __restrict__ mask, const float* __restrict__ corr,
             const int* __restrict__ gen, const int* __restrict__ off,
             float* __restrict__ out, int BN) {
  int c = blockIdx.x, dg = blockIdx.y, m = blockIdx.z;
  int g = gen[c];
  if (g == 0) return;
  int t = threadIdx.x, q = t >> 6, lane = t & 63;
  int d0 = dg * 256 + lane * 4;
  const float* wb = W2 + (size_t)m * HH * DD + d0;
  const float* ac = act + ((size_t)m * CC + c) * HH;
  float4 a = {0.f, 0.f, 0.f, 0.f};
  int j0 = q * (HH / 4);
  for (int j = j0; j < j0 + HH / 4; j += 4) {
    float a0 = ac[j], a1 = ac[j + 1], a2 = ac[j + 2], a3 = ac[j + 3];
    const float4 w0 = *reinterpret_cast<const float4*>(wb + (size_t)j * DD);
    const float4 w1 = *reinterpret_cast<const float4*>(wb + (size_t)(j + 1) * DD);
    const float4 w2 = *reinterpret_cast<const float4*>(wb + (size_t)(j + 2) * DD);
    const float4 w3 = *reinterpret_cast<const float4*>(wb + (size_t)(j + 3) * DD);
    a.x = fmaf(a0, w0.x, a.x); a.y = fmaf(a0, w0.y, a.y);
    a.z = fmaf(a0, w0.z, a.z); a.w = fmaf(a0, w0.w, a.w);
    a.x = fmaf(a1, w1.x, a.x); a.y = fmaf(a1, w1.y, a.y);
    a.z = fmaf(a1, w1.z, a.z); a.w = fmaf(a1, w1.w, a.w);
    a.x = fmaf(a2, w2.x, a.x); a.y = fmaf(a2, w2.y, a.y);
    a.z = fmaf(a2, w2.z, a.z); a.w = fmaf(a2, w2.w, a.w);
    a.x = fmaf(a3, w3.x, a.x); a.y = fmaf(a3, w3.y, a.y);
    a.z = fmaf(a3, w3.z, a.z); a.w = fmaf(a3, w3.w, a.w);
  }
  __shared__ float4 red[4][64];
  red[q][lane] = a;
  __syncthreads();
  if (q == 0) {
    float4 s = red[0][lane];
    const float4 s1 = red[1][lane], s2 = red[2][lane], s3 = red[3][lane];
    s.x += s1.x + s2.x + s3.x;
    s.y += s1.y + s2.y + s3.y;
    s.z += s1.z + s2.z + s3.z;
    s.w += s1.w + s2.w + s3.w;
    const float4 bb = *reinterpret_cast<const float4*>(&b2[m * DD + d0]);
    s.x += bb.x; s.y += bb.y; s.z += bb.z; s.w += bb.w;
#pragma unroll
    for (int om = 0; om < MM; ++om) {
      if (om == m) continue;
      float al = corr[m * MM + om] * mask[c * MM + om];
      float ia = 1.f - al;
      const float4 p = *reinterpret_cast<const float4*>(
          &proto[((size_t)c * MM + om) * DD + d0]);
      s.x = s.x * ia + p.x * al;
      s.y = s.y * ia + p.y * al;
      s.z = s.z * ia + p.z * al;
      s.w = s.w * ia + p.w * al;
    }
    int row0 = BB + off[c];
    for (int k = 0; k < g; ++k)
      *reinterpret_cast<float4*>(&out[((size_t)m * BN + row0 + k) * DD + d0]) = s;
  }
}

}  // namespace

extern "C" void kernel_launch(void* const* d_in, const int* in_sizes, int n_in,
                              void* d_out, int out_size, void* d_ws, size_t ws_size,
                              hipStream_t stream) {
  const float* features = (const float*)d_in[0];
  const float* fused    = (const float*)d_in[1];
  const int*   labels   = (const int*)d_in[2];
  const float* W1       = (const float*)d_in[3];
  const float* b1       = (const float*)d_in[4];
  const float* lng      = (const float*)d_in[5];
  const float* lnb      = (const float*)d_in[6];
  const float* W2       = (const float*)d_in[7];
  const float* b2       = (const float*)d_in[8];
  const float* corr     = (const float*)d_in[9];
  const float* dw       = (const float*)d_in[10];
  float* out = (float*)d_out;
  char*  ws  = (char*)d_ws;

  const int BN = (out_size - 1) / (MM * DD + 1);  // B + N
  const int N  = BN - BB;
  const size_t L0 = (size_t)MM * BN * DD;         // start of combined_labels

  int*   counts  = (int*)(ws + WS_COUNTS);
  int*   gen     = (int*)(ws + WS_GEN);
  int*   off     = (int*)(ws + WS_OFF);
  float* bpart   = (float*)(ws + WS_BPART);
  float* mask    = (float*)(ws + WS_MASK);
  float* proto   = (float*)(ws + WS_PROTO);
  int*   rowlist = (int*)(ws + WS_ROWLIST);
  float* act     = (float*)(ws + WS_ACT);
  float* psum    = (float*)(ws + WS_PSUM);

  k_plan_all<<<1, 1024, 0, stream>>>(labels, dw, counts, gen, off, rowlist,
                                     out + L0, out + L0 + BB, out + L0 + BN, N);
  k_mega1<<<NMEGA1, 256, 0, stream>>>(features, fused, W1, rowlist, counts,
                                      out, psum, bpart, BN);
  k_mega2<<<2 * CC * MM, 256, 0, stream>>>(psum, counts, bpart, W1, b1, lng,
                                           lnb, proto, mask, act);
  k_gemm_final<<<dim3(CC, 4, MM), 256, 0, stream>>>(act, W2, b2, proto, mask,
                                                    corr, gen, off, out, BN);
}

// Round 5
// 226.328 us; speedup vs baseline: 1.1680x; 1.1680x over previous
//
#include <hip/hip_runtime.h>

namespace {

constexpr int MM = 3;
constexpr int BB = 16384;
constexpr int DD = 1024;
constexpr int CC = 100;
constexpr int HH = 2048;             // 2*DD
constexpr int DESIRED = BB / CC;     // 163
constexpr int RLS = 2048;            // rowlist stride per class
constexpr int RS  = 8;               // gather row-chunks per (c,m)

// gather kernel block partition
constexpr int NGATH = CC * MM * RS;           // 2400 read-only gather blocks
constexpr int DBS   = 4;                      // base d-splits
constexpr int NBASE = (HH / 256) * DBS * MM;  // 96
// copy kernel block partition
constexpr int NCOPY = 1536;                   // 512 per modality
// class-GEMM geometry (W2 read exactly once)
constexpr int KC  = 16, JL = HH / KC;   // 128 j per block
constexpr int DG2 = 4,  DR2 = 256;      // 4 d-groups of 256
constexpr int CSPL = 4, CH = CC / CSPL; // 4x25 class split

// ws byte offsets (aliased; max footprint 23.45 MB)
constexpr size_t WS_COUNTS  = 0;            // 128 int  (memset to 0)
constexpr size_t WS_GEN     = 512;          // 128 int
constexpr size_t WS_OFF     = 1024;         // 128 int
constexpr size_t WS_BPART   = 2048;         // DBS*MM*HH f32 (96 KB)
constexpr size_t WS_MASK    = 100352;       // CC*MM f32
constexpr size_t WS_PROTO   = 102400;       // CC*MM*DD f32 (1.2 MB)
constexpr size_t WS_SHARED  = 1331200;      // rowlist int[CC*RLS] (800 KB) -> act f32[MM*HH*CC] (2.4 MB)
constexpr size_t WS_BIG     = 3788800;      // psum f32[CC*MM*RS*DD] (9.8 MB) -> gpart f32 (19.66 MB)

// count + bin rows by class + float labels for combined_labels[:B]
__global__ void __launch_bounds__(256)
k_count(const int* __restrict__ labels, int* __restrict__ counts,
        int* __restrict__ rowlist, float* __restrict__ out_lab) {
  int b = blockIdx.x * 256 + threadIdx.x;
  if (b < BB) {
    int l = labels[b];
    int pos = atomicAdd(&counts[l], 1);
    if (pos < RLS) rowlist[l * RLS + pos] = b;
    out_lab[b] = (float)l;
  }
}

// one block: gen/off prefix scan, tail labels via binary search, loss
__global__ void __launch_bounds__(128)
k_plan(const int* __restrict__ counts, int* __restrict__ gen, int* __restrict__ off,
       float* __restrict__ out_lab_tail, float* __restrict__ out_loss,
       const float* __restrict__ dw, int N) {
  __shared__ int s[128], soff[CC + 1];
  int t = threadIdx.x;
  int cnt = (t < CC) ? counts[t] : 0;
  int g = (t < CC && cnt > 0) ? max(DESIRED - cnt, 0) : 0;
  s[t] = g;
  __syncthreads();
  for (int o = 1; o < 128; o <<= 1) {
    int v = (t >= o) ? s[t - o] : 0;
    __syncthreads();
    s[t] += v;
    __syncthreads();
  }
  int excl = s[t] - g;
  if (t < CC) {
    gen[t] = g;
    off[t] = excl;
    soff[t] = excl;
  }
  if (t == 0) {
    soff[CC] = N;
    *out_loss = (N > 0) ? 0.1f * dw[0] : 0.0f;
  }
  __syncthreads();
  for (int i = t; i < N; i += 128) {
    int lo = 0, hi = CC;
    while (hi - lo > 1) {
      int mid = (lo + hi) >> 1;
      if (soff[mid] <= i) lo = mid; else hi = mid;
    }
    out_lab_tail[i] = (float)lo;
  }
}

// Phase 1 (read-only): class gather partial sums -> psum; base partials.
// Side effect: streams all of `features` through L3 (stays resident, 201 MB).
__global__ void __launch_bounds__(256)
k_gather(const float* __restrict__ feat, const float* __restrict__ fused,
         const float* __restrict__ W1, const int* __restrict__ rowlist,
         const int* __restrict__ counts, float* __restrict__ psum,
         float* __restrict__ bpart) {
  int bid = blockIdx.x, t = threadIdx.x;
  if (bid < NGATH) {
    int c = bid % CC, mrs = bid / CC;
    int m = mrs % MM, rs = mrs / MM;
    int cnt = min(counts[c], RLS);
    int lo = (cnt * rs) / RS, hi = (cnt * (rs + 1)) / RS;
    const int* rl = rowlist + c * RLS;
    int d0 = t * 4;
    const float* fb = feat + (size_t)m * BB * DD + d0;
    float4 a = {0.f, 0.f, 0.f, 0.f};
    int i = lo;
    for (; i + 4 <= hi; i += 4) {
      int r0 = rl[i], r1 = rl[i + 1], r2 = rl[i + 2], r3 = rl[i + 3];
      const float4 v0 = *reinterpret_cast<const float4*>(fb + (size_t)r0 * DD);
      const float4 v1 = *reinterpret_cast<const float4*>(fb + (size_t)r1 * DD);
      const float4 v2 = *reinterpret_cast<const float4*>(fb + (size_t)r2 * DD);
      const float4 v3 = *reinterpret_cast<const float4*>(fb + (size_t)r3 * DD);
      a.x += v0.x + v1.x + v2.x + v3.x;
      a.y += v0.y + v1.y + v2.y + v3.y;
      a.z += v0.z + v1.z + v2.z + v3.z;
      a.w += v0.w + v1.w + v2.w + v3.w;
    }
    for (; i < hi; ++i) {
      const float4 v = *reinterpret_cast<const float4*>(fb + (size_t)rl[i] * DD);
      a.x += v.x; a.y += v.y; a.z += v.z; a.w += v.w;
    }
    *reinterpret_cast<float4*>(
        &psum[(((size_t)c * MM + m) * RS + rs) * DD + d0]) = a;
  } else {
    // bpart[db][m][j] = sum_{d in chunk} fused[d] * W1[m][d][j]
    int b3 = bid - NGATH;
    int jb = b3 % (HH / 256), db = (b3 / (HH / 256)) % DBS,
        m = b3 / ((HH / 256) * DBS);
    int j = jb * 256 + t;
    const float* w = W1 + ((size_t)m * (DD + CC)) * HH + j;
    float acc = 0.f;
    int dlo = db * (DD / DBS);
#pragma unroll 8
    for (int d = dlo; d < dlo + DD / DBS; ++d)
      acc = fmaf(fused[d], w[(size_t)d * HH], acc);
    bpart[((size_t)db * MM + m) * HH + j] = acc;
  }
}

// Phase 2: sequential copy (reads L3-warm features) || proto+mask || LN-act.
__global__ void __launch_bounds__(256)
k_copy(const float* __restrict__ feat, const float* __restrict__ psum,
       const int* __restrict__ counts, const float* __restrict__ bpart,
       const float* __restrict__ W1, const float* __restrict__ b1,
       const float* __restrict__ lng, const float* __restrict__ lnb,
       float* __restrict__ out, float* __restrict__ proto,
       float* __restrict__ mask, float* __restrict__ act, int BN) {
  __shared__ float r1[256], r2[256];
  int bid = blockIdx.x, t = threadIdx.x;
  if (bid < NCOPY) {
    int m = bid / 512, cb = bid % 512;
    const float4* src = reinterpret_cast<const float4*>(feat + (size_t)m * BB * DD);
    float4* dst = reinterpret_cast<float4*>(out + (size_t)m * BN * DD);
    size_t i0 = (size_t)cb * 256 + t;
    constexpr size_t S = 512 * 256;
#pragma unroll
    for (int k = 0; k < 8; ++k) {
      float4 v0 = src[i0 + (4 * k + 0) * S];
      float4 v1 = src[i0 + (4 * k + 1) * S];
      float4 v2 = src[i0 + (4 * k + 2) * S];
      float4 v3 = src[i0 + (4 * k + 3) * S];
      dst[i0 + (4 * k + 0) * S] = v0;
      dst[i0 + (4 * k + 1) * S] = v1;
      dst[i0 + (4 * k + 2) * S] = v2;
      dst[i0 + (4 * k + 3) * S] = v3;
    }
  } else if (bid < NCOPY + CC * MM) {
    // proto + mask
    int b2 = bid - NCOPY;
    int c = b2 % CC, m = b2 / CC;
    int d0 = t * 4;
    float4 a = {0.f, 0.f, 0.f, 0.f};
#pragma unroll
    for (int rs = 0; rs < RS; ++rs) {
      const float4 v = *reinterpret_cast<const float4*>(
          &psum[(((size_t)c * MM + m) * RS + rs) * DD + d0]);
      a.x += v.x; a.y += v.y; a.z += v.z; a.w += v.w;
    }
    int cnt = counts[c];
    float inv = cnt > 0 ? 1.f / (float)cnt : 0.f;
    a.x *= inv; a.y *= inv; a.z *= inv; a.w *= inv;
    *reinterpret_cast<float4*>(&proto[((size_t)c * MM + m) * DD + d0]) = a;
    r1[t] = a.x + a.y + a.z + a.w;
    __syncthreads();
    for (int o = 128; o > 0; o >>= 1) {
      if (t < o) r1[t] += r1[t + o];
      __syncthreads();
    }
    if (t == 0) mask[c * MM + m] = (r1[0] > 0.f) ? 1.f : 0.f;
  } else {
    // h = base + W1[m][D+c] + b1 -> LN -> leaky -> act[m][j][c]
    int b2 = bid - NCOPY - CC * MM;
    int c = b2 % CC, m = b2 / CC;
    const float* w1row = W1 + ((size_t)m * (DD + CC) + DD + c) * HH;
    float h[8];
    float s = 0.f, s2 = 0.f;
#pragma unroll
    for (int k = 0; k < 8; ++k) {
      int j = t + k * 256;
      float base = bpart[(size_t)(0 * MM + m) * HH + j]
                 + bpart[(size_t)(1 * MM + m) * HH + j]
                 + bpart[(size_t)(2 * MM + m) * HH + j]
                 + bpart[(size_t)(3 * MM + m) * HH + j];
      float v = base + w1row[j] + b1[m * HH + j];
      h[k] = v; s += v; s2 += v * v;
    }
    r1[t] = s; r2[t] = s2;
    __syncthreads();
    for (int o = 128; o > 0; o >>= 1) {
      if (t < o) { r1[t] += r1[t + o]; r2[t] += r2[t + o]; }
      __syncthreads();
    }
    float mu = r1[0] * (1.f / HH);
    float var = r2[0] * (1.f / HH) - mu * mu;
    float rstd = rsqrtf(var + 1e-5f);
    float* ao = act + (size_t)m * HH * CC;
#pragma unroll
    for (int k = 0; k < 8; ++k) {
      int j = t + k * 256;
      float v = (h[k] - mu) * rstd * lng[m * HH + j] + lnb[m * HH + j];
      v = v > 0.f ? v : 0.2f * v;
      ao[(size_t)j * CC + c] = v;   // [m][j][c] for uniform scalar gemm reads
    }
  }
}

// gpart[m][dg][kc][c][d'] = sum_{j in chunk} act[m][j][c] * W2[m][j][d]
// W2 read exactly once across the grid. 4-way class split -> 768 blocks.
__global__ void __launch_bounds__(256)
k_gemm(const float* __restrict__ act, const float* __restrict__ W2,
       float* __restrict__ gpart) {
  int dg = blockIdx.x, kc = blockIdx.y;
  int m = blockIdx.z >> 2, ch = blockIdx.z & 3;
  int t = threadIdx.x;
  int d = dg * DR2 + t;
  int j0 = kc * JL, c0 = ch * CH;
  float acc[CH];
#pragma unroll
  for (int c = 0; c < CH; ++c) acc[c] = 0.f;
  const float* ab = act + ((size_t)m * HH + j0) * CC + c0;
  const float* wb = W2 + ((size_t)m * HH + j0) * DD + d;
  for (int j = 0; j < JL; ++j) {
    float w2v = wb[(size_t)j * DD];
    const float* aj = ab + (size_t)j * CC;   // uniform -> scalar loads
#pragma unroll
    for (int c = 0; c < CH; ++c) acc[c] = fmaf(aj[c], w2v, acc[c]);
  }
  float* pb = gpart + ((size_t)(m * DG2 + dg) * KC + kc) * (CC * DR2)
            + (size_t)c0 * DR2 + t;
#pragma unroll
  for (int c = 0; c < CH; ++c) pb[(size_t)c * DR2] = acc[c];
}

// g = sum_kc gpart + b2 -> blend with protos -> scatter to rows of class c
__global__ void __launch_bounds__(256)
k_final(const float* __restrict__ gpart, const float* __restrict__ proto,
        const float* __restrict__ mask, const float* __restrict__ b2,
        const float* __restrict__ corr, const int* __restrict__ gen,
        const int* __restrict__ off, float* __restrict__ out, int BN) {
  int c = blockIdx.x, m = blockIdx.y, t = threadIdx.x;
  int g = gen[c];
  if (g == 0) return;
  int d0 = t * 4, dg = d0 >> 8, dsub = d0 & 255;
  float4 a = {0.f, 0.f, 0.f, 0.f};
#pragma unroll
  for (int kc = 0; kc < KC; ++kc) {
    const float4 v = *reinterpret_cast<const float4*>(
        &gpart[((size_t)(m * DG2 + dg) * KC + kc) * (CC * DR2) + c * DR2 + dsub]);
    a.x += v.x; a.y += v.y; a.z += v.z; a.w += v.w;
  }
  const float4 bb = *reinterpret_cast<const float4*>(&b2[m * DD + d0]);
  a.x += bb.x; a.y += bb.y; a.z += bb.z; a.w += bb.w;
#pragma unroll
  for (int om = 0; om < MM; ++om) {
    if (om == m) continue;
    float al = corr[m * MM + om] * mask[c * MM + om];
    float ia = 1.f - al;
    const float4 p = *reinterpret_cast<const float4*>(
        &proto[((size_t)c * MM + om) * DD + d0]);
    a.x = a.x * ia + p.x * al;
    a.y = a.y * ia + p.y * al;
    a.z = a.z * ia + p.z * al;
    a.w = a.w * ia + p.w * al;
  }
  int row0 = BB + off[c];
  for (int k = 0; k < g; ++k)
    *reinterpret_cast<float4*>(&out[((size_t)m * BN + row0 + k) * DD + d0]) = a;
}

}  // namespace

extern "C" void kernel_launch(void* const* d_in, const int* in_sizes, int n_in,
                              void* d_out, int out_size, void* d_ws, size_t ws_size,
                              hipStream_t stream) {
  const float* features = (const float*)d_in[0];
  const float* fused    = (const float*)d_in[1];
  const int*   labels   = (const int*)d_in[2];
  const float* W1       = (const float*)d_in[3];
  const float* b1       = (const float*)d_in[4];
  const float* lng      = (const float*)d_in[5];
  const float* lnb      = (const float*)d_in[6];
  const float* W2       = (const float*)d_in[7];
  const float* b2       = (const float*)d_in[8];
  const float* corr     = (const float*)d_in[9];
  const float* dw       = (const float*)d_in[10];
  float* out = (float*)d_out;
  char*  ws  = (char*)d_ws;

  const int BN = (out_size - 1) / (MM * DD + 1);  // B + N
  const int N  = BN - BB;
  const size_t L0 = (size_t)MM * BN * DD;         // start of combined_labels

  int*   counts  = (int*)(ws + WS_COUNTS);
  int*   gen     = (int*)(ws + WS_GEN);
  int*   off     = (int*)(ws + WS_OFF);
  float* bpart   = (float*)(ws + WS_BPART);
  float* mask    = (float*)(ws + WS_MASK);
  float* proto   = (float*)(ws + WS_PROTO);
  int*   rowlist = (int*)(ws + WS_SHARED);   // dead after k_gather
  float* act     = (float*)(ws + WS_SHARED); // live k_copy..k_gemm
  float* psum    = (float*)(ws + WS_BIG);    // dead after k_copy
  float* gpart   = (float*)(ws + WS_BIG);    // live k_gemm..k_final

  hipMemsetAsync(counts, 0, 512, stream);
  k_count<<<BB / 256, 256, 0, stream>>>(labels, counts, rowlist, out + L0);
  k_plan<<<1, 128, 0, stream>>>(counts, gen, off, out + L0 + BB, out + L0 + BN,
                                dw, N);
  k_gather<<<NGATH + NBASE, 256, 0, stream>>>(features, fused, W1, rowlist,
                                              counts, psum, bpart);
  k_copy<<<NCOPY + 2 * CC * MM, 256, 0, stream>>>(features, psum, counts, bpart,
                                                  W1, b1, lng, lnb, out, proto,
                                                  mask, act, BN);
  k_gemm<<<dim3(DG2, KC, MM * CSPL), 256, 0, stream>>>(act, W2, gpart);
  k_final<<<dim3(CC, MM), 256, 0, stream>>>(gpart, proto, mask, b2, corr,
                                            gen, off, out, BN);
}

// Round 7
// 173.223 us; speedup vs baseline: 1.5261x; 1.3066x over previous
//
#include <hip/hip_runtime.h>

namespace {

typedef float f4v __attribute__((ext_vector_type(4)));

constexpr int MM = 3;
constexpr int BB = 16384;
constexpr int DD = 1024;
constexpr int CC = 100;
constexpr int HH = 2048;             // 2*DD
constexpr int DESIRED = BB / CC;     // 163
constexpr int RLS = 2048;            // rowlist stride per class
constexpr int RS  = 4;               // gather row-chunks per (c,m)
constexpr int NB  = BB / 256;        // 64 label blocks

// gather kernel block partition
constexpr int NGATH = CC * MM * RS;           // 1200 gather blocks
constexpr int DBS   = 4;                      // base d-splits
constexpr int NBASE = (HH / 256) * DBS * MM;  // 96
// class-GEMM geometry (W2 read exactly once)
constexpr int KC  = 16, JL = HH / KC;   // 128 j per block
constexpr int DG2 = 4,  DR2 = 256;      // 4 d-groups of 256
constexpr int CSPL = 4, CH = CC / CSPL; // 4x25 class split

// ws byte offsets (aliased; max footprint ~22.5 MB)
constexpr size_t WS_COUNTS  = 0;            // 128 int
constexpr size_t WS_GEN     = 512;          // 128 int
constexpr size_t WS_OFF     = 1024;         // 128 int
constexpr size_t WS_BHIST   = 4096;         // NB*128 int (32 KB)
constexpr size_t WS_BLKBASE = 36864;        // NB*128 int (32 KB)
constexpr size_t WS_BPART   = 69632;        // DBS*MM*HH f32 (96 KB)
constexpr size_t WS_MASK    = 167936;       // CC*MM f32
constexpr size_t WS_PROTO   = 172032;       // CC*MM*DD f32 (1.2 MB)
constexpr size_t WS_SHARED  = 1433600;      // rowlist int[CC*RLS] (800 KB) -> act f32[MM*HH*CC] (2.4 MB)
constexpr size_t WS_BIG     = 3932160;      // psum f32[CC*MM*RS*DD] (4.9 MB) -> gpart f32 (19.66 MB)

// Per-block label histogram (LDS atomics -> exact integer counts) + head labels.
__global__ void __launch_bounds__(256)
k_hist(const int* __restrict__ labels, int* __restrict__ bhist,
       float* __restrict__ out_lab) {
  __shared__ int h[128];
  int blk = blockIdx.x, t = threadIdx.x;
  if (t < 128) h[t] = 0;
  __syncthreads();
  int b = blk * 256 + t;
  int l = labels[b];
  atomicAdd(&h[l], 1);
  out_lab[b] = (float)l;
  __syncthreads();
  if (t < 128) bhist[blk * 128 + t] = h[t];
}

// One block: per-class block-prefix (blkbase), counts, gen/off scan,
// tail labels via binary search, loss. Fully deterministic.
__global__ void __launch_bounds__(128)
k_plan(const int* __restrict__ bhist, int* __restrict__ blkbase,
       int* __restrict__ counts, int* __restrict__ gen, int* __restrict__ off,
       float* __restrict__ out_lab_tail, float* __restrict__ out_loss,
       const float* __restrict__ dw, int N) {
  __shared__ int s[128], soff[CC + 1];
  int t = threadIdx.x;
  int run = 0;
  if (t < 128) {
    for (int blk = 0; blk < NB; ++blk) {
      blkbase[blk * 128 + t] = run;
      run += bhist[blk * 128 + t];
    }
    counts[t] = run;
  }
  int cnt = (t < CC) ? run : 0;
  int g = (t < CC && cnt > 0) ? max(DESIRED - cnt, 0) : 0;
  s[t] = g;
  __syncthreads();
  for (int o = 1; o < 128; o <<= 1) {
    int v = (t >= o) ? s[t - o] : 0;
    __syncthreads();
    s[t] += v;
    __syncthreads();
  }
  int excl = s[t] - g;
  if (t < CC) {
    gen[t] = g;
    off[t] = excl;
    soff[t] = excl;
  }
  if (t == 0) {
    soff[CC] = N;
    *out_loss = (N > 0) ? 0.1f * dw[0] : 0.0f;
  }
  __syncthreads();
  for (int i = t; i < N; i += 128) {
    int lo = 0, hi = CC;
    while (hi - lo > 1) {
      int mid = (lo + hi) >> 1;
      if (soff[mid] <= i) lo = mid; else hi = mid;
    }
    out_lab_tail[i] = (float)lo;
  }
}

// Stable scatter: row b's slot = blkbase[blk][l] + (# earlier rows in this
// block with same label). Bit-deterministic rowlist (sorted by b).
__global__ void __launch_bounds__(256)
k_scatter(const int* __restrict__ labels, const int* __restrict__ blkbase,
          int* __restrict__ rowlist) {
  __shared__ int lab[256];
  int blk = blockIdx.x, t = threadIdx.x;
  int b = blk * 256 + t;
  int myl = labels[b];
  lab[t] = myl;
  __syncthreads();
  int rank = 0;
  for (int u = 0; u < t; ++u) rank += (lab[u] == myl) ? 1 : 0;
  int pos = blkbase[blk * 128 + myl] + rank;
  if (pos < RLS) rowlist[myl * RLS + pos] = b;
}

// Fused gather: features copy + register class-sum partials -> psum
// (8-row read burst then write burst, plain ld/st). || base matvec partials.
__global__ void __launch_bounds__(256)
k_gather(const float* __restrict__ feat, const float* __restrict__ fused,
         const float* __restrict__ W1, const int* __restrict__ rowlist,
         const int* __restrict__ counts, float* __restrict__ out,
         float* __restrict__ psum, float* __restrict__ bpart, int BN) {
  int bid = blockIdx.x, t = threadIdx.x;
  if (bid < NGATH) {
    int c = bid % CC, mrs = bid / CC;
    int m = mrs % MM, rs = mrs / MM;
    int cnt = min(counts[c], RLS);
    int lo = (cnt * rs) / RS, hi = (cnt * (rs + 1)) / RS;
    const int* rl = rowlist + c * RLS;
    int d0 = t * 4;
    const float* fb = feat + (size_t)m * BB * DD + d0;
    float* ob = out + (size_t)m * BN * DD + d0;
    f4v a = {0.f, 0.f, 0.f, 0.f};
    int i = lo;
    for (; i + 8 <= hi; i += 8) {
      int r0 = rl[i + 0], r1 = rl[i + 1], r2 = rl[i + 2], r3 = rl[i + 3];
      int r4 = rl[i + 4], r5 = rl[i + 5], r6 = rl[i + 6], r7 = rl[i + 7];
      const f4v v0 = *(const f4v*)(fb + (size_t)r0 * DD);
      const f4v v1 = *(const f4v*)(fb + (size_t)r1 * DD);
      const f4v v2 = *(const f4v*)(fb + (size_t)r2 * DD);
      const f4v v3 = *(const f4v*)(fb + (size_t)r3 * DD);
      const f4v v4 = *(const f4v*)(fb + (size_t)r4 * DD);
      const f4v v5 = *(const f4v*)(fb + (size_t)r5 * DD);
      const f4v v6 = *(const f4v*)(fb + (size_t)r6 * DD);
      const f4v v7 = *(const f4v*)(fb + (size_t)r7 * DD);
      *(f4v*)(ob + (size_t)r0 * DD) = v0;
      *(f4v*)(ob + (size_t)r1 * DD) = v1;
      *(f4v*)(ob + (size_t)r2 * DD) = v2;
      *(f4v*)(ob + (size_t)r3 * DD) = v3;
      *(f4v*)(ob + (size_t)r4 * DD) = v4;
      *(f4v*)(ob + (size_t)r5 * DD) = v5;
      *(f4v*)(ob + (size_t)r6 * DD) = v6;
      *(f4v*)(ob + (size_t)r7 * DD) = v7;
      a += v0 + v1 + v2 + v3 + v4 + v5 + v6 + v7;
    }
    for (; i < hi; ++i) {
      int r = rl[i];
      const f4v v = *(const f4v*)(fb + (size_t)r * DD);
      *(f4v*)(ob + (size_t)r * DD) = v;
      a += v;
    }
    *(f4v*)(&psum[(((size_t)c * MM + m) * RS + rs) * DD + d0]) = a;
  } else {
    // bpart[db][m][j] = sum_{d in chunk} fused[d] * W1[m][d][j]
    int b3 = bid - NGATH;
    int jb = b3 % (HH / 256), db = (b3 / (HH / 256)) % DBS,
        m = b3 / ((HH / 256) * DBS);
    int j = jb * 256 + t;
    const float* w = W1 + ((size_t)m * (DD + CC)) * HH + j;
    float acc = 0.f;
    int dlo = db * (DD / DBS);
#pragma unroll 8
    for (int d = dlo; d < dlo + DD / DBS; ++d)
      acc = fmaf(fused[d], w[(size_t)d * HH], acc);
    bpart[((size_t)db * MM + m) * HH + j] = acc;
  }
}

// proto+mask (blocks 0..299)  ||  LN-activation -> act[m][j][c] (blocks 300..599)
__global__ void __launch_bounds__(256)
k_mega2(const float* __restrict__ psum, const int* __restrict__ counts,
        const float* __restrict__ bpart, const float* __restrict__ W1,
        const float* __restrict__ b1, const float* __restrict__ lng,
        const float* __restrict__ lnb, float* __restrict__ proto,
        float* __restrict__ mask, float* __restrict__ act) {
  __shared__ float r1[256], r2[256];
  int bid = blockIdx.x, t = threadIdx.x;
  if (bid < CC * MM) {
    int c = bid % CC, m = bid / CC;
    int d0 = t * 4;
    f4v a = {0.f, 0.f, 0.f, 0.f};
#pragma unroll
    for (int rs = 0; rs < RS; ++rs)
      a += *(const f4v*)(&psum[(((size_t)c * MM + m) * RS + rs) * DD + d0]);
    int cnt = counts[c];
    float inv = cnt > 0 ? 1.f / (float)cnt : 0.f;
    a *= inv;
    *(f4v*)(&proto[((size_t)c * MM + m) * DD + d0]) = a;
    r1[t] = a.x + a.y + a.z + a.w;
    __syncthreads();
    for (int o = 128; o > 0; o >>= 1) {
      if (t < o) r1[t] += r1[t + o];
      __syncthreads();
    }
    if (t == 0) mask[c * MM + m] = (r1[0] > 0.f) ? 1.f : 0.f;
  } else {
    // h = base + W1[m][D+c] + b1 -> LN -> leaky -> act[m][j][c]
    int b2 = bid - CC * MM;
    int c = b2 % CC, m = b2 / CC;
    const float* w1row = W1 + ((size_t)m * (DD + CC) + DD + c) * HH;
    float h[8];
    float s = 0.f, s2 = 0.f;
#pragma unroll
    for (int k = 0; k < 8; ++k) {
      int j = t + k * 256;
      float base = bpart[(size_t)(0 * MM + m) * HH + j]
                 + bpart[(size_t)(1 * MM + m) * HH + j]
                 + bpart[(size_t)(2 * MM + m) * HH + j]
                 + bpart[(size_t)(3 * MM + m) * HH + j];
      float v = base + w1row[j] + b1[m * HH + j];
      h[k] = v; s += v; s2 += v * v;
    }
    r1[t] = s; r2[t] = s2;
    __syncthreads();
    for (int o = 128; o > 0; o >>= 1) {
      if (t < o) { r1[t] += r1[t + o]; r2[t] += r2[t + o]; }
      __syncthreads();
    }
    float mu = r1[0] * (1.f / HH);
    float var = r2[0] * (1.f / HH) - mu * mu;
    float rstd = rsqrtf(var + 1e-5f);
    float* ao = act + (size_t)m * HH * CC;
#pragma unroll
    for (int k = 0; k < 8; ++k) {
      int j = t + k * 256;
      float v = (h[k] - mu) * rstd * lng[m * HH + j] + lnb[m * HH + j];
      v = v > 0.f ? v : 0.2f * v;
      ao[(size_t)j * CC + c] = v;   // [m][j][c] for uniform scalar gemm reads
    }
  }
}

// gpart[m][dg][kc][c][d'] = sum_{j in chunk} act[m][j][c] * W2[m][j][d]
// W2 read exactly once across the grid. 4-way class split -> 768 blocks.
__global__ void __launch_bounds__(256)
k_gemm(const float* __restrict__ act, const float* __restrict__ W2,
       float* __restrict__ gpart) {
  int dg = blockIdx.x, kc = blockIdx.y;
  int m = blockIdx.z >> 2, ch = blockIdx.z & 3;
  int t = threadIdx.x;
  int d = dg * DR2 + t;
  int j0 = kc * JL, c0 = ch * CH;
  float acc[CH];
#pragma unroll
  for (int c = 0; c < CH; ++c) acc[c] = 0.f;
  const float* ab = act + ((size_t)m * HH + j0) * CC + c0;
  const float* wb = W2 + ((size_t)m * HH + j0) * DD + d;
  for (int j = 0; j < JL; ++j) {
    float w2v = wb[(size_t)j * DD];
    const float* aj = ab + (size_t)j * CC;   // uniform -> scalar loads
#pragma unroll
    for (int c = 0; c < CH; ++c) acc[c] = fmaf(aj[c], w2v, acc[c]);
  }
  float* pb = gpart + ((size_t)(m * DG2 + dg) * KC + kc) * (CC * DR2)
            + (size_t)c0 * DR2 + t;
#pragma unroll
  for (int c = 0; c < CH; ++c) pb[(size_t)c * DR2] = acc[c];
}

// g = sum_kc gpart + b2 -> blend with protos -> scatter to rows of class c
__global__ void __launch_bounds__(256)
k_final(const float* __restrict__ gpart, const float* __restrict__ proto,
        const float* __restrict__ mask, const float* __restrict__ b2,
        const float* __restrict__ corr, const int* __restrict__ gen,
        const int* __restrict__ off, float* __restrict__ out, int BN) {
  int c = blockIdx.x, m = blockIdx.y, t = threadIdx.x;
  int g = gen[c];
  if (g == 0) return;
  int d0 = t * 4, dg = d0 >> 8, dsub = d0 & 255;
  f4v a = {0.f, 0.f, 0.f, 0.f};
#pragma unroll
  for (int kc = 0; kc < KC; ++kc)
    a += *(const f4v*)(&gpart[((size_t)(m * DG2 + dg) * KC + kc) * (CC * DR2)
                              + c * DR2 + dsub]);
  a += *(const f4v*)(&b2[m * DD + d0]);
#pragma unroll
  for (int om = 0; om < MM; ++om) {
    if (om == m) continue;
    float al = corr[m * MM + om] * mask[c * MM + om];
    float ia = 1.f - al;
    const f4v p = *(const f4v*)(&proto[((size_t)c * MM + om) * DD + d0]);
    a = a * ia + p * al;
  }
  int row0 = BB + off[c];
  for (int k = 0; k < g; ++k)
    *(f4v*)(&out[((size_t)m * BN + row0 + k) * DD + d0]) = a;
}

}  // namespace

extern "C" void kernel_launch(void* const* d_in, const int* in_sizes, int n_in,
                              void* d_out, int out_size, void* d_ws, size_t ws_size,
                              hipStream_t stream) {
  const float* features = (const float*)d_in[0];
  const float* fused    = (const float*)d_in[1];
  const int*   labels   = (const int*)d_in[2];
  const float* W1       = (const float*)d_in[3];
  const float* b1       = (const float*)d_in[4];
  const float* lng      = (const float*)d_in[5];
  const float* lnb      = (const float*)d_in[6];
  const float* W2       = (const float*)d_in[7];
  const float* b2       = (const float*)d_in[8];
  const float* corr     = (const float*)d_in[9];
  const float* dw       = (const float*)d_in[10];
  float* out = (float*)d_out;
  char*  ws  = (char*)d_ws;

  const int BN = (out_size - 1) / (MM * DD + 1);  // B + N
  const int N  = BN - BB;
  const size_t L0 = (size_t)MM * BN * DD;         // start of combined_labels

  int*   counts  = (int*)(ws + WS_COUNTS);
  int*   gen     = (int*)(ws + WS_GEN);
  int*   off     = (int*)(ws + WS_OFF);
  int*   bhist   = (int*)(ws + WS_BHIST);
  int*   blkbase = (int*)(ws + WS_BLKBASE);
  float* bpart   = (float*)(ws + WS_BPART);
  float* mask    = (float*)(ws + WS_MASK);
  float* proto   = (float*)(ws + WS_PROTO);
  int*   rowlist = (int*)(ws + WS_SHARED);   // dead after k_gather
  float* act     = (float*)(ws + WS_SHARED); // live k_mega2..k_gemm
  float* psum    = (float*)(ws + WS_BIG);    // dead after k_mega2
  float* gpart   = (float*)(ws + WS_BIG);    // live k_gemm..k_final

  k_hist<<<NB, 256, 0, stream>>>(labels, bhist, out + L0);
  k_plan<<<1, 128, 0, stream>>>(bhist, blkbase, counts, gen, off,
                                out + L0 + BB, out + L0 + BN, dw, N);
  k_scatter<<<NB, 256, 0, stream>>>(labels, blkbase, rowlist);
  k_gather<<<NGATH + NBASE, 256, 0, stream>>>(features, fused, W1, rowlist,
                                              counts, out, psum, bpart, BN);
  k_mega2<<<2 * CC * MM, 256, 0, stream>>>(psum, counts, bpart, W1, b1, lng,
                                           lnb, proto, mask, act);
  k_gemm<<<dim3(DG2, KC, MM * CSPL), 256, 0, stream>>>(act, W2, gpart);
  k_final<<<dim3(CC, MM), 256, 0, stream>>>(gpart, proto, mask, b2, corr,
                                            gen, off, out, BN);
}